// Round 15
// baseline (42.902 us; speedup 1.0000x reference)
//
#include <hip/hip_runtime.h>

#define TPB 256

// Pade-13 coefficients (float32, matching reference `b = _PADE_B.astype(A.dtype)`)
#define B0c  6.476475253248e+16f
#define B1c  3.238237626624e+16f
#define B2c  7.7717703038976e+15f
#define B3c  1.1873537964288e+15f
#define B4c  1.29060195264e+14f
#define B5c  1.05594705216e+13f
#define B6c  6.704425728e+11f
#define B7c  3.352212864e+10f
#define B8c  1.32324192e+9f
#define B9c  4.08408e+7f
#define B10c 9.6096e+5f
#define B11c 1.638e+4f
#define B12c 182.0f
#define B13c 1.0f

// True vector type so __builtin_nontemporal_load applies (float4 is a struct).
typedef float __attribute__((ext_vector_type(4))) f32x4;
__device__ __forceinline__ f32x4 ntload(const f32x4* p) {
  return __builtin_nontemporal_load(p);
}

// Verified Cayley-Hamilton pipeline for ONE 3x3 matrix (absmax 0.0 since r5).
// Straight-line named scalars ONLY: any runtime loop around this body trips
// the allocator cliff (r6/r7/r14: VGPR collapses to 24-28 + full scratch
// spill). No atomics/fences (r6/7/11: device-wide publication always lost).
__device__ __forceinline__ float expm_loss_one(
    float a0, float a1, float a2, float a3, float a4, float a5,
    float a6, float a7, float a8, float d0, float d1, float d2) {
  const float detA = a0 * (a4 * a8 - a5 * a7)
                   - a1 * (a3 * a8 - a5 * a6)
                   + a2 * (a3 * a7 - a4 * a6);
  const float trA = a0 + a4 + a8;
  const float trA2 = fmaf(a0, a0, fmaf(a4, a4, a8 * a8))
                   + 2.0f * (fmaf(a1, a3, fmaf(a2, a6, a5 * a7)));
  float fro2 = fmaf(a0, a0, fmaf(a1, a1, a2 * a2));
  fro2 = fmaf(a3, a3, fmaf(a4, a4, fmaf(a5, a5, fro2)));
  fro2 = fmaf(a6, a6, fmaf(a7, a7, fmaf(a8, a8, fro2)));
  const float u0 = fmaf(a0, d0, fmaf(a1, d1, a2 * d2));
  const float u1 = fmaf(a3, d0, fmaf(a4, d1, a5 * d2));
  const float u2 = fmaf(a6, d0, fmaf(a7, d1, a8 * d2));
  const float v0 = fmaf(a0, d0, fmaf(a3, d1, a6 * d2));
  const float v1 = fmaf(a1, d0, fmaf(a4, d1, a7 * d2));
  const float v2 = fmaf(a2, d0, fmaf(a5, d1, a8 * d2));
  const float dAd  = fmaf(d0, u0, fmaf(d1, u1, d2 * u2));
  const float dA2d = fmaf(v0, u0, fmaf(v1, u1, v2 * u2));
  const float dd   = fmaf(d0, d0, fmaf(d1, d1, d2 * d2));

  const float nsqf = fmaxf(0.0f, ceilf(fmaf(0.5f, __log2f(fro2), -2.4253625f)));
  int nsq = (int)nsqf;
  nsq = nsq > 6 ? 6 : nsq;
  const float scl = exp2f(-nsqf);
  const float scl2 = scl * scl;

  const float t = scl * trA;
  const float trB2 = scl2 * trA2;
  const float m = 0.5f * fmaf(t, t, -trB2);
  const float dch = detA * scl2 * scl;

  const float x4p = fmaf(t, t, -m), x4q = fmaf(-t, m, dch), x4r = t * dch;
  const float x5p = fmaf(x4p, t, x4q), x5q = fmaf(-x4p, m, x4r), x5r = x4p * dch;
  const float x6p = fmaf(x5p, t, x5q), x6q = fmaf(-x5p, m, x5r), x6r = x5p * dch;

  const float w1p = fmaf(B11c, x4p, x6p) + B9c;
  const float w1q = fmaf(B11c, x4q, x6q);
  const float w1r = fmaf(B11c, x4r, x6r);
  const float s4a = x6p * w1p;
  const float s3a = fmaf(x6p, w1q, x6q * w1p);
  const float gp = fmaf(s4a, x4p, fmaf(s3a, t,   fmaf(x6p, w1r, fmaf(x6r, w1p, x6q * w1q))));
  const float gq = fmaf(s4a, x4q, fmaf(-s3a, m,  fmaf(x6q, w1r, x6r * w1q)));
  const float gr = fmaf(s4a, x4r, fmaf(s3a, dch, x6r * w1r));
  const float uep = fmaf(B7c, x6p, fmaf(B5c, x4p, gp)) + B3c;
  const float ueq = fmaf(B7c, x6q, fmaf(B5c, x4q, gq));
  const float uer = fmaf(B7c, x6r, fmaf(B5c, x4r, gr)) + B1c;
  const float up = fmaf(uep, t, ueq);
  const float uq = fmaf(-uep, m, uer);
  const float ur = uep * dch;

  const float w2p = fmaf(B12c, x6p, fmaf(B10c, x4p, B8c));
  const float w2q = fmaf(B12c, x6q, B10c * x4q);
  const float w2r = fmaf(B12c, x6r, B10c * x4r);
  const float s4b = x6p * w2p;
  const float s3b = fmaf(x6p, w2q, x6q * w2p);
  const float hp = fmaf(s4b, x4p, fmaf(s3b, t,   fmaf(x6p, w2r, fmaf(x6r, w2p, x6q * w2q))));
  const float hq = fmaf(s4b, x4q, fmaf(-s3b, m,  fmaf(x6q, w2r, x6r * w2q)));
  const float hr = fmaf(s4b, x4r, fmaf(s3b, dch, x6r * w2r));
  const float vp = fmaf(B6c, x6p, fmaf(B4c, x4p, hp)) + B2c;
  const float vq = fmaf(B6c, x6q, fmaf(B4c, x4q, hq));
  const float vr = fmaf(B6c, x6r, fmaf(B4c, x4r, hr)) + B0c;

  const float s = 1.0f / B0c;
  const float pp = (vp + up) * s, pq = (vq + uq) * s, pr = (vr + ur) * s;
  const float qp = (vp - up) * s, qq = (vq - uq) * s, qr = (vr - ur) * s;

  const float qpp = qp * qp, qpq2 = 2.0f * qp * qq;
  const float a2t = fmaf(qpp, x4p, fmaf(qpq2, t,   fmaf(2.0f * qp, qr, qq * qq)));
  const float b2t = fmaf(qpp, x4q, fmaf(-qpq2, m,  2.0f * qq * qr));
  const float c2t = fmaf(qpp, x4r, fmaf(qpq2, dch, qr * qr));
  const float tQ = fmaf(qp, trB2, fmaf(qq, t, 3.0f * qr));
  const float trQ2 = fmaf(a2t, trB2, fmaf(b2t, t, 3.0f * c2t));
  const float mQ = 0.5f * fmaf(tQ, tQ, -trQ2);
  const float detQ =
      qp * (fmaf(qp, fmaf(qp, dch * dch, fmaf(qq, m * dch, qr * fmaf(m, m, -2.0f * t * dch))),
                 fmaf(qq, fmaf(qq, t * dch, qr * fmaf(t, m, -3.0f * dch)),
                      qr * qr * fmaf(t, t, -2.0f * m))))
    + qq * fmaf(qq, fmaf(qq, dch, qr * m), qr * qr * t)
    + qr * qr * qr;
  float inv = __builtin_amdgcn_rcpf(detQ);
  inv = inv * (2.0f - detQ * inv);
  const float jp = fmaf(-tQ, qp, a2t);
  const float jq = fmaf(-tQ, qq, b2t);
  const float jr = fmaf(-tQ, qr, c2t) + mQ;

  const float s4 = pp * jp;
  const float s3 = fmaf(pp, jq, pq * jp);
  float rp = fmaf(s4, x4p, fmaf(s3, t,   fmaf(pp, jr, fmaf(pr, jp, pq * jq)))) * inv;
  float rq = fmaf(s4, x4q, fmaf(-s3, m,  fmaf(pq, jr, pr * jq))) * inv;
  float rr = fmaf(s4, x4r, fmaf(s3, dch, pr * jr)) * inv;

  for (int k = 0; k < nsq; ++k) {
    const float rp2 = rp * rp, rpq2 = 2.0f * rp * rq;
    const float nrp = fmaf(rp2, x4p, fmaf(rpq2, t,   fmaf(2.0f * rp, rr, rq * rq)));
    const float nrq = fmaf(rp2, x4q, fmaf(-rpq2, m,  2.0f * rq * rr));
    const float nrr = fmaf(rp2, x4r, fmaf(rpq2, dch, rr * rr));
    rp = nrp; rq = nrq; rr = nrr;
  }

  const float quad = fmaf(rp, scl2 * dA2d, fmaf(rq, scl * dAd, rr * dd));
  return 0.5f * (quad + detA);
}

// r8 structure (best measured: 23.9us) with NONTEMPORAL streaming loads:
// inputs are read exactly once per launch; `nt` skips cache-line allocation
// on the read stream (the one untested read-path mechanism).
__global__ __launch_bounds__(TPB) void expm_loss_kernel(
    const float* __restrict__ mean, const float* __restrict__ var,
    const float* __restrict__ gt, float* __restrict__ partials) {
  const int tid = threadIdx.x;
  const long long ti = (long long)blockIdx.x * TPB + tid;

  const f32x4* vp = (const f32x4*)var + ti * 9;
  const f32x4 w0 = ntload(vp + 0), w1 = ntload(vp + 1), w2 = ntload(vp + 2),
              w3 = ntload(vp + 3), w4 = ntload(vp + 4), w5 = ntload(vp + 5),
              w6 = ntload(vp + 6), w7 = ntload(vp + 7), w8 = ntload(vp + 8);
  const f32x4* mp = (const f32x4*)mean + ti * 3;
  const f32x4* gp = (const f32x4*)gt + ti * 3;
  const f32x4 mw0 = ntload(mp + 0), mw1 = ntload(mp + 1), mw2 = ntload(mp + 2);
  const f32x4 gw0 = ntload(gp + 0), gw1 = ntload(gp + 1), gw2 = ntload(gp + 2);

  float val = expm_loss_one(w0.x, w0.y, w0.z, w0.w, w1.x, w1.y, w1.z, w1.w, w2.x,
                            gw0.x - mw0.x, gw0.y - mw0.y, gw0.z - mw0.z);
  val += expm_loss_one(w2.y, w2.z, w2.w, w3.x, w3.y, w3.z, w3.w, w4.x, w4.y,
                       gw0.w - mw0.w, gw1.x - mw1.x, gw1.y - mw1.y);
  val += expm_loss_one(w4.z, w4.w, w5.x, w5.y, w5.z, w5.w, w6.x, w6.y, w6.z,
                       gw1.z - mw1.z, gw1.w - mw1.w, gw2.x - mw2.x);
  val += expm_loss_one(w6.w, w7.x, w7.y, w7.z, w7.w, w8.x, w8.y, w8.z, w8.w,
                       gw2.y - mw2.y, gw2.z - mw2.z, gw2.w - mw2.w);

  // --- fixed-tree block reduction (deterministic) ---
#pragma unroll
  for (int offx = 32; offx > 0; offx >>= 1) val += __shfl_down(val, offx, 64);
  __shared__ float wsum[TPB / 64];
  if ((tid & 63) == 0) wsum[tid >> 6] = val;
  __syncthreads();
  if (tid == 0) {
    float b = 0.f;
#pragma unroll
    for (int wi = 0; wi < TPB / 64; ++wi) b += wsum[wi];
    partials[blockIdx.x] = b;
  }
}

// Single-wave tail: 1536 partials = 384 float4 = 6 float4/lane. No LDS, no
// barriers -- one shuffle tree, lane 0 stores.
__global__ __launch_bounds__(64) void reduce_partials_kernel(
    const float* __restrict__ partials, double inv_total,
    float* __restrict__ out) {
  const int lane = threadIdx.x;
  const float4* p4 = (const float4*)partials;
  double s = 0.0;
#pragma unroll
  for (int k = 0; k < 6; ++k) {
    const float4 v = p4[lane + k * 64];
    s += (double)v.x + (double)v.y + (double)v.z + (double)v.w;
  }
#pragma unroll
  for (int off = 32; off > 0; off >>= 1) s += __shfl_down(s, off, 64);
  if (lane == 0) out[0] = (float)(s * inv_total);
}

extern "C" void kernel_launch(void* const* d_in, const int* in_sizes, int n_in,
                              void* d_out, int out_size, void* d_ws, size_t ws_size,
                              hipStream_t stream) {
  const float* mean = (const float*)d_in[0];
  const float* var  = (const float*)d_in[1];
  const float* gt   = (const float*)d_in[2];
  const int nmat    = in_sizes[1] / 9;       // 1,572,864 (divisible by 1024)
  const int nblocks = nmat / (TPB * 4);      // 1536
  float* partials   = (float*)d_ws;          // 1536 floats

  expm_loss_kernel<<<nblocks, TPB, 0, stream>>>(mean, var, gt, partials);
  reduce_partials_kernel<<<1, 64, 0, stream>>>(partials, 1.0 / (double)nmat,
                                               (float*)d_out);
}

// Round 16
// 23.736 us; speedup vs baseline: 1.8075x; 1.8075x over previous
//
#include <hip/hip_runtime.h>

#define TPB 256

// Pade-13 coefficients (float32, matching reference `b = _PADE_B.astype(A.dtype)`)
#define B0c  6.476475253248e+16f
#define B1c  3.238237626624e+16f
#define B2c  7.7717703038976e+15f
#define B3c  1.1873537964288e+15f
#define B4c  1.29060195264e+14f
#define B5c  1.05594705216e+13f
#define B6c  6.704425728e+11f
#define B7c  3.352212864e+10f
#define B8c  1.32324192e+9f
#define B9c  4.08408e+7f
#define B10c 9.6096e+5f
#define B11c 1.638e+4f
#define B12c 182.0f
#define B13c 1.0f

// Verified Cayley-Hamilton pipeline for ONE 3x3 matrix (absmax 0.0 since r5).
// Straight-line named scalars ONLY: runtime loops (r14), fused tails (r6/r7),
// and ext_vector nt-loads (r15) all trip an allocator cliff (VGPR 24-56 +
// full scratch spill). No atomics/fences (r6/7/11: device-wide publication
// always lost to the plain two-kernel tail on this 8-XCD part).
__device__ __forceinline__ float expm_loss_one(
    float a0, float a1, float a2, float a3, float a4, float a5,
    float a6, float a7, float a8, float d0, float d1, float d2) {
  const float detA = a0 * (a4 * a8 - a5 * a7)
                   - a1 * (a3 * a8 - a5 * a6)
                   + a2 * (a3 * a7 - a4 * a6);
  const float trA = a0 + a4 + a8;
  const float trA2 = fmaf(a0, a0, fmaf(a4, a4, a8 * a8))
                   + 2.0f * (fmaf(a1, a3, fmaf(a2, a6, a5 * a7)));
  float fro2 = fmaf(a0, a0, fmaf(a1, a1, a2 * a2));
  fro2 = fmaf(a3, a3, fmaf(a4, a4, fmaf(a5, a5, fro2)));
  fro2 = fmaf(a6, a6, fmaf(a7, a7, fmaf(a8, a8, fro2)));
  const float u0 = fmaf(a0, d0, fmaf(a1, d1, a2 * d2));
  const float u1 = fmaf(a3, d0, fmaf(a4, d1, a5 * d2));
  const float u2 = fmaf(a6, d0, fmaf(a7, d1, a8 * d2));
  const float v0 = fmaf(a0, d0, fmaf(a3, d1, a6 * d2));
  const float v1 = fmaf(a1, d0, fmaf(a4, d1, a7 * d2));
  const float v2 = fmaf(a2, d0, fmaf(a5, d1, a8 * d2));
  const float dAd  = fmaf(d0, u0, fmaf(d1, u1, d2 * u2));
  const float dA2d = fmaf(v0, u0, fmaf(v1, u1, v2 * u2));
  const float dd   = fmaf(d0, d0, fmaf(d1, d1, d2 * d2));

  const float nsqf = fmaxf(0.0f, ceilf(fmaf(0.5f, __log2f(fro2), -2.4253625f)));
  int nsq = (int)nsqf;
  nsq = nsq > 6 ? 6 : nsq;
  const float scl = exp2f(-nsqf);
  const float scl2 = scl * scl;

  const float t = scl * trA;
  const float trB2 = scl2 * trA2;
  const float m = 0.5f * fmaf(t, t, -trB2);
  const float dch = detA * scl2 * scl;

  const float x4p = fmaf(t, t, -m), x4q = fmaf(-t, m, dch), x4r = t * dch;
  const float x5p = fmaf(x4p, t, x4q), x5q = fmaf(-x4p, m, x4r), x5r = x4p * dch;
  const float x6p = fmaf(x5p, t, x5q), x6q = fmaf(-x5p, m, x5r), x6r = x5p * dch;

  const float w1p = fmaf(B11c, x4p, x6p) + B9c;
  const float w1q = fmaf(B11c, x4q, x6q);
  const float w1r = fmaf(B11c, x4r, x6r);
  const float s4a = x6p * w1p;
  const float s3a = fmaf(x6p, w1q, x6q * w1p);
  const float gp = fmaf(s4a, x4p, fmaf(s3a, t,   fmaf(x6p, w1r, fmaf(x6r, w1p, x6q * w1q))));
  const float gq = fmaf(s4a, x4q, fmaf(-s3a, m,  fmaf(x6q, w1r, x6r * w1q)));
  const float gr = fmaf(s4a, x4r, fmaf(s3a, dch, x6r * w1r));
  const float uep = fmaf(B7c, x6p, fmaf(B5c, x4p, gp)) + B3c;
  const float ueq = fmaf(B7c, x6q, fmaf(B5c, x4q, gq));
  const float uer = fmaf(B7c, x6r, fmaf(B5c, x4r, gr)) + B1c;
  const float up = fmaf(uep, t, ueq);
  const float uq = fmaf(-uep, m, uer);
  const float ur = uep * dch;

  const float w2p = fmaf(B12c, x6p, fmaf(B10c, x4p, B8c));
  const float w2q = fmaf(B12c, x6q, B10c * x4q);
  const float w2r = fmaf(B12c, x6r, B10c * x4r);
  const float s4b = x6p * w2p;
  const float s3b = fmaf(x6p, w2q, x6q * w2p);
  const float hp = fmaf(s4b, x4p, fmaf(s3b, t,   fmaf(x6p, w2r, fmaf(x6r, w2p, x6q * w2q))));
  const float hq = fmaf(s4b, x4q, fmaf(-s3b, m,  fmaf(x6q, w2r, x6r * w2q)));
  const float hr = fmaf(s4b, x4r, fmaf(s3b, dch, x6r * w2r));
  const float vp = fmaf(B6c, x6p, fmaf(B4c, x4p, hp)) + B2c;
  const float vq = fmaf(B6c, x6q, fmaf(B4c, x4q, hq));
  const float vr = fmaf(B6c, x6r, fmaf(B4c, x4r, hr)) + B0c;

  const float s = 1.0f / B0c;
  const float pp = (vp + up) * s, pq = (vq + uq) * s, pr = (vr + ur) * s;
  const float qp = (vp - up) * s, qq = (vq - uq) * s, qr = (vr - ur) * s;

  const float qpp = qp * qp, qpq2 = 2.0f * qp * qq;
  const float a2t = fmaf(qpp, x4p, fmaf(qpq2, t,   fmaf(2.0f * qp, qr, qq * qq)));
  const float b2t = fmaf(qpp, x4q, fmaf(-qpq2, m,  2.0f * qq * qr));
  const float c2t = fmaf(qpp, x4r, fmaf(qpq2, dch, qr * qr));
  const float tQ = fmaf(qp, trB2, fmaf(qq, t, 3.0f * qr));
  const float trQ2 = fmaf(a2t, trB2, fmaf(b2t, t, 3.0f * c2t));
  const float mQ = 0.5f * fmaf(tQ, tQ, -trQ2);
  const float detQ =
      qp * (fmaf(qp, fmaf(qp, dch * dch, fmaf(qq, m * dch, qr * fmaf(m, m, -2.0f * t * dch))),
                 fmaf(qq, fmaf(qq, t * dch, qr * fmaf(t, m, -3.0f * dch)),
                      qr * qr * fmaf(t, t, -2.0f * m))))
    + qq * fmaf(qq, fmaf(qq, dch, qr * m), qr * qr * t)
    + qr * qr * qr;
  float inv = __builtin_amdgcn_rcpf(detQ);
  inv = inv * (2.0f - detQ * inv);
  const float jp = fmaf(-tQ, qp, a2t);
  const float jq = fmaf(-tQ, qq, b2t);
  const float jr = fmaf(-tQ, qr, c2t) + mQ;

  const float s4 = pp * jp;
  const float s3 = fmaf(pp, jq, pq * jp);
  float rp = fmaf(s4, x4p, fmaf(s3, t,   fmaf(pp, jr, fmaf(pr, jp, pq * jq)))) * inv;
  float rq = fmaf(s4, x4q, fmaf(-s3, m,  fmaf(pq, jr, pr * jq))) * inv;
  float rr = fmaf(s4, x4r, fmaf(s3, dch, pr * jr)) * inv;

  for (int k = 0; k < nsq; ++k) {
    const float rp2 = rp * rp, rpq2 = 2.0f * rp * rq;
    const float nrp = fmaf(rp2, x4p, fmaf(rpq2, t,   fmaf(2.0f * rp, rr, rq * rq)));
    const float nrq = fmaf(rp2, x4q, fmaf(-rpq2, m,  2.0f * rq * rr));
    const float nrr = fmaf(rp2, x4r, fmaf(rpq2, dch, rr * rr));
    rp = nrp; rq = nrq; rr = nrr;
  }

  const float quad = fmaf(rp, scl2 * dA2d, fmaf(rq, scl * dAd, rr * dd));
  return 0.5f * (quad + detA);
}

// r8 structure verbatim (best measured: 23.9us): 4 mats/thread, 36 var floats
// = exactly 9 aligned float4, 12 mean/gt floats = exactly 3 float4 each.
// Fully unrolled straight-line body; default cached loads.
__global__ __launch_bounds__(TPB) void expm_loss_kernel(
    const float* __restrict__ mean, const float* __restrict__ var,
    const float* __restrict__ gt, float* __restrict__ partials) {
  const int tid = threadIdx.x;
  const long long ti = (long long)blockIdx.x * TPB + tid;

  const float4* vp = (const float4*)var + ti * 9;
  const float4 w0 = vp[0], w1 = vp[1], w2 = vp[2], w3 = vp[3], w4 = vp[4],
               w5 = vp[5], w6 = vp[6], w7 = vp[7], w8 = vp[8];
  const float4* mp = (const float4*)mean + ti * 3;
  const float4* gp = (const float4*)gt + ti * 3;
  const float4 mw0 = mp[0], mw1 = mp[1], mw2 = mp[2];
  const float4 gw0 = gp[0], gw1 = gp[1], gw2 = gp[2];

  float val = expm_loss_one(w0.x, w0.y, w0.z, w0.w, w1.x, w1.y, w1.z, w1.w, w2.x,
                            gw0.x - mw0.x, gw0.y - mw0.y, gw0.z - mw0.z);
  val += expm_loss_one(w2.y, w2.z, w2.w, w3.x, w3.y, w3.z, w3.w, w4.x, w4.y,
                       gw0.w - mw0.w, gw1.x - mw1.x, gw1.y - mw1.y);
  val += expm_loss_one(w4.z, w4.w, w5.x, w5.y, w5.z, w5.w, w6.x, w6.y, w6.z,
                       gw1.z - mw1.z, gw1.w - mw1.w, gw2.x - mw2.x);
  val += expm_loss_one(w6.w, w7.x, w7.y, w7.z, w7.w, w8.x, w8.y, w8.z, w8.w,
                       gw2.y - mw2.y, gw2.z - mw2.z, gw2.w - mw2.w);

  // --- fixed-tree block reduction (deterministic) ---
#pragma unroll
  for (int offx = 32; offx > 0; offx >>= 1) val += __shfl_down(val, offx, 64);
  __shared__ float wsum[TPB / 64];
  if ((tid & 63) == 0) wsum[tid >> 6] = val;
  __syncthreads();
  if (tid == 0) {
    float b = 0.f;
#pragma unroll
    for (int wi = 0; wi < TPB / 64; ++wi) b += wsum[wi];
    partials[blockIdx.x] = b;
  }
}

__global__ __launch_bounds__(256) void reduce_partials_kernel(
    const float* __restrict__ partials, int n, double inv_total,
    float* __restrict__ out) {
  double s = 0.0;
  for (int i = threadIdx.x; i < n; i += 256) s += (double)partials[i];
#pragma unroll
  for (int off = 32; off > 0; off >>= 1) s += __shfl_down(s, off, 64);
  __shared__ double ds[4];
  if ((threadIdx.x & 63) == 0) ds[threadIdx.x >> 6] = s;
  __syncthreads();
  if (threadIdx.x == 0)
    out[0] = (float)((ds[0] + ds[1] + ds[2] + ds[3]) * inv_total);
}

extern "C" void kernel_launch(void* const* d_in, const int* in_sizes, int n_in,
                              void* d_out, int out_size, void* d_ws, size_t ws_size,
                              hipStream_t stream) {
  const float* mean = (const float*)d_in[0];
  const float* var  = (const float*)d_in[1];
  const float* gt   = (const float*)d_in[2];
  const int nmat    = in_sizes[1] / 9;       // 1,572,864 (divisible by 1024)
  const int nblocks = nmat / (TPB * 4);      // 1536
  float* partials   = (float*)d_ws;          // 1536 floats

  expm_loss_kernel<<<nblocks, TPB, 0, stream>>>(mean, var, gt, partials);
  reduce_partials_kernel<<<1, 256, 0, stream>>>(partials, nblocks,
                                                1.0 / (double)nmat,
                                                (float*)d_out);
}